// Round 5
// baseline (262.050 us; speedup 1.0000x reference)
//
#include <hip/hip_runtime.h>
#include <hip/hip_bf16.h>

// E3TAOBackflow on MI355X — MFMA bf16, register-resident norms/gating.
// Reduction (verified R2/R3): antisymmetrization => scalar out = 0 exactly,
// vector out = (v @ [Wh0@Wu0]) * sigmoid([s,||v@Wh0||] @ Wm0 + bm0) @ C,
// C = Wh1@Wu1@W1/sqrt(S).  Wm1, bm1, W0 dead.  Output f32.
// R8: back to R0 skeleton (non-aliased LDS 34560B, (256,4)) + two changes:
// (1) lgkm-only barriers (s_waitcnt lgkmcnt(0); s_barrier) — no barrier here
//     has a global-mem dependence, so the compiler's vmcnt(0) drain at
//     __syncthreads was pure stall (R6 showed 16KB of stores at a barrier
//     cost ~13us). Stores now NEVER block at barriers.
// (2) 2-group pipeline: grid 1024, block does groups bid and bid+1024.
//     g1 loads issue right after B1(g0) (latency+read traffic hidden under
//     g0 compute); g1 LDS staging after B3(g0) (xa/xv dead, v1 separate
//     buffer so phase3(g0) unaffected); g0 stores drain under g1 compute.
// Phase1 kept split (Vh pass / Vu pass) for VGPR headroom with 32 held
// staging regs; zeros post-B3 (drain under phase3 MFMA, no barrier after).

typedef __attribute__((ext_vector_type(8))) short short8;
typedef __attribute__((ext_vector_type(4))) float floatx4;

static __device__ __forceinline__ unsigned short f2bf(float f) {
  unsigned u = __float_as_uint(f);
  u = (u + 0x7fffu + ((u >> 16) & 1u)) >> 16;  // RNE
  return (unsigned short)u;
}
static __device__ __forceinline__ unsigned pk2(float lo, float hi) {
  __hip_bfloat162 h = __float22bfloat162_rn(make_float2(lo, hi));
  return *(unsigned*)&h;  // low 16 = lo
}

// write element B[k][n] into swizzled fragment layout (KT = K/32)
static __device__ __forceinline__ void put_sw(unsigned short* B, int k, int n,
                                              float val, int KT) {
  int kt = k >> 5, quad = (k >> 3) & 3, j = k & 7;
  int nt = n >> 4, c = n & 15;
  int lane = quad * 16 + c;
  B[(((nt * KT + kt) * 64 + lane) << 3) + j] = f2bf(val);
}

// ---- prep1: Wcat = [Wh0 | Wh0@Wu0] -> Wcat_sw (128x256, KT=4); T = Wh1@Wu1
__global__ __launch_bounds__(128) void prep1(
    const float* __restrict__ Wh0, const float* __restrict__ Wu0,
    const float* __restrict__ Wh1, const float* __restrict__ Wu1,
    unsigned short* __restrict__ Wcat_sw, float* __restrict__ T) {
  int b = blockIdx.x, o = threadIdx.x;
  if (b < 128) {
    int m = b;
    float acc = 0.f;
    for (int h = 0; h < 128; ++h) acc += Wh0[m * 128 + h] * Wu0[h * 128 + o];
    put_sw(Wcat_sw, m, o, Wh0[m * 128 + o], 4);
    put_sw(Wcat_sw, m, o + 128, acc, 4);
  } else {
    int m = b - 128;
    float acc = 0.f;
    for (int h = 0; h < 128; ++h) acc += Wh1[m * 128 + h] * Wu1[h * 128 + o];
    T[m * 128 + o] = acc;
  }
}

// ---- prep2: C_sw = (T@W1)/sqrt(S) (128x256, KT=4); Wm0_sw (256x128, KT=8)
__global__ __launch_bounds__(256) void prep2(
    const float* __restrict__ T, const float* __restrict__ W1,
    const float* __restrict__ Wm0, unsigned short* __restrict__ C_sw,
    unsigned short* __restrict__ Wm0_sw) {
  int b = blockIdx.x, tid = threadIdx.x;
  if (b < 128) {
    int m = b, n = tid;
    float acc = 0.f;
    for (int h = 0; h < 128; ++h) acc += T[m * 128 + h] * W1[h * 256 + n];
    put_sw(C_sw, m, n, acc * 0.08838834764831845f, 4);
  } else {
    int k = (b - 128) * 2 + (tid >> 7);
    int n = tid & 127;
    put_sw(Wm0_sw, k, n, Wm0[k * 128 + n], 8);
  }
}

#define XA_S 264  // bf16 row stride for xa (256 + 8 pad; 528B = 33*16 ok)
#define XV_S 136  // bf16 row stride for xv/v1 (128 + 8 pad; 272B = 17*16 ok)
#define XV_T 2176 // elements per t-plane (16 * 136)

// Barrier with LDS-only drain: each wave waits its own ds ops, then syncs.
// No vmcnt drain -> outstanding global stores/loads flow across freely.
// sched_barrier(0) fences stop hipcc hoisting ds ops across the asm (rule 18).
static __device__ __forceinline__ void lds_barrier() {
  __builtin_amdgcn_sched_barrier(0);
  asm volatile("s_waitcnt lgkmcnt(0)" ::: "memory");
  __builtin_amdgcn_s_barrier();
  __builtin_amdgcn_sched_barrier(0);
}

static __device__ __forceinline__ void load_x(const float* __restrict__ xrow,
                                              int tid, float4* st_s,
                                              float4* st_v) {
#pragma unroll
  for (int i = 0; i < 2; ++i) {  // s: 512 float4 chunks
    int e = tid + 256 * i;
    int r = e >> 5, c0 = (e & 31) << 2;
    st_s[i] = *(const float4*)(xrow + r * 512 + c0);
  }
#pragma unroll
  for (int i = 0; i < 2; ++i) {  // v: 512 chunks of 12 floats (4 m x 3 t)
    int e = tid + 256 * i;
    int r = e >> 5, mc = e & 31;
    const float* p = xrow + r * 512 + 128 + mc * 12;
    st_v[3 * i + 0] = *(const float4*)(p);
    st_v[3 * i + 1] = *(const float4*)(p + 4);
    st_v[3 * i + 2] = *(const float4*)(p + 8);
  }
}

static __device__ __forceinline__ void stage_write(int tid, const float4* st_s,
                                                   const float4* st_v,
                                                   unsigned short* xa,
                                                   unsigned short* xv) {
#pragma unroll
  for (int i = 0; i < 2; ++i) {
    int e = tid + 256 * i;
    int r = e >> 5, c0 = (e & 31) << 2;
    uint2 p = make_uint2(pk2(st_s[i].x, st_s[i].y), pk2(st_s[i].z, st_s[i].w));
    *(uint2*)(xa + r * XA_S + c0) = p;
  }
#pragma unroll
  for (int i = 0; i < 2; ++i) {
    int e = tid + 256 * i;
    int r = e >> 5, mc = e & 31;
    float4 a = st_v[3 * i + 0], b = st_v[3 * i + 1], c = st_v[3 * i + 2];
    float f[12] = {a.x, a.y, a.z, a.w, b.x, b.y, b.z, b.w, c.x, c.y, c.z, c.w};
#pragma unroll
    for (int t = 0; t < 3; ++t) {
      uint2 pk = make_uint2(pk2(f[t], f[t + 3]), pk2(f[t + 6], f[t + 9]));
      *(uint2*)(xv + t * XV_T + r * XV_S + mc * 4) = pk;
    }
  }
}

// phase1a -> norms -> phase1b -> B2 -> gate -> v1 writes (caller does B3)
static __device__ __forceinline__ void compute_front(
    const unsigned short* __restrict__ Wcat_sw,
    const unsigned short* __restrict__ Wm0_sw, unsigned short* xa,
    unsigned short* xv, unsigned short* v1, int lane, int w, int l15, int quad,
    float bias0, float bias1) {
  const int ntg[4] = {2 * w, 2 * w + 1, 8 + 2 * w, 9 + 2 * w};
  const floatx4 zf4 = {0.f, 0.f, 0.f, 0.f};

  // phase1a: per t, Vh(16x32) = xv_t(16x128) @ Wcat[:, ntg01]
  floatx4 accH[3][2];
#pragma unroll
  for (int t = 0; t < 3; ++t)
#pragma unroll
    for (int j = 0; j < 2; ++j) accH[t][j] = zf4;
  for (int kt = 0; kt < 4; ++kt) {
    short8 bf[2];
#pragma unroll
    for (int j = 0; j < 2; ++j)
      bf[j] = *(const short8*)(Wcat_sw + (((ntg[j] * 4 + kt) * 64 + lane) << 3));
#pragma unroll
    for (int t = 0; t < 3; ++t) {
      short8 af = *(const short8*)(xv + t * XV_T + l15 * XV_S + kt * 32 + quad * 8);
#pragma unroll
      for (int j = 0; j < 2; ++j)
        accH[t][j] = __builtin_amdgcn_mfma_f32_16x16x32_bf16(af, bf[j], accH[t][j], 0, 0, 0);
    }
  }

  // norms: vn = sqrt(sum_t Vh_t^2 + eps) -> xa[:,128:]
#pragma unroll
  for (int j = 0; j < 2; ++j)
#pragma unroll
    for (int rg = 0; rg < 4; ++rg) {
      float s0 = accH[0][j][rg], s1 = accH[1][j][rg], s2 = accH[2][j][rg];
      float vn = sqrtf(s0 * s0 + s1 * s1 + s2 * s2 + 1e-8f);
      int r = quad * 4 + rg;
      int h = ntg[j] * 16 + l15;
      xa[r * XA_S + 128 + h] = f2bf(vn);
    }

  // phase1b: per t, Vu(16x32) = xv_t(16x128) @ Wcat[:, ntg23]
  floatx4 accU[3][2];
#pragma unroll
  for (int t = 0; t < 3; ++t)
#pragma unroll
    for (int j = 0; j < 2; ++j) accU[t][j] = zf4;
  for (int kt = 0; kt < 4; ++kt) {
    short8 bf[2];
#pragma unroll
    for (int j = 0; j < 2; ++j)
      bf[j] = *(const short8*)(Wcat_sw + (((ntg[2 + j] * 4 + kt) * 64 + lane) << 3));
#pragma unroll
    for (int t = 0; t < 3; ++t) {
      short8 af = *(const short8*)(xv + t * XV_T + l15 * XV_S + kt * 32 + quad * 8);
#pragma unroll
      for (int j = 0; j < 2; ++j)
        accU[t][j] = __builtin_amdgcn_mfma_f32_16x16x32_bf16(af, bf[j], accU[t][j], 0, 0, 0);
    }
  }
  lds_barrier();  // B2

  // gate GEMM: sm(16x128) = [s|vn](16x256) @ Wm0; wave w -> cols 2w,2w+1
  floatx4 ga[2] = {zf4, zf4};
  for (int kt = 0; kt < 8; ++kt) {
    short8 af = *(const short8*)(xa + l15 * XA_S + kt * 32 + quad * 8);
    short8 b0 = *(const short8*)(Wm0_sw + ((((2 * w) * 8 + kt) * 64 + lane) << 3));
    short8 b1 = *(const short8*)(Wm0_sw + ((((2 * w + 1) * 8 + kt) * 64 + lane) << 3));
    ga[0] = __builtin_amdgcn_mfma_f32_16x16x32_bf16(af, b0, ga[0], 0, 0, 0);
    ga[1] = __builtin_amdgcn_mfma_f32_16x16x32_bf16(af, b1, ga[1], 0, 0, 0);
  }
  float g[2][4];
#pragma unroll
  for (int j = 0; j < 2; ++j) {
    float bias = j ? bias1 : bias0;
#pragma unroll
    for (int rg = 0; rg < 4; ++rg)
      g[j][rg] = 1.f / (1.f + __expf(-(ga[j][rg] + bias)));
  }
#pragma unroll
  for (int t = 0; t < 3; ++t)
#pragma unroll
    for (int j = 0; j < 2; ++j)
#pragma unroll
      for (int rg = 0; rg < 4; ++rg) {
        int r = quad * 4 + rg;
        int o = (2 * w + j) * 16 + l15;  // Vu col within [0,128)
        v1[t * XV_T + r * XV_S + o] = f2bf(accU[t][j][rg] * g[j][rg]);
      }
}

// zeros -> phase3 (two halves) -> data stores. No barrier after.
static __device__ __forceinline__ void compute_back(
    const unsigned short* __restrict__ C_sw, const unsigned short* v1,
    float* __restrict__ orow, int tid, int lane, int w, int l15, int quad) {
  const int ntg[4] = {2 * w, 2 * w + 1, 8 + 2 * w, 9 + 2 * w};
  const floatx4 zf4 = {0.f, 0.f, 0.f, 0.f};
#pragma unroll
  for (int i = 0; i < 4; ++i) {  // zeros: 1024 float4
    int e = tid + 256 * i;
    int r = e >> 6, gblk = (e >> 2) & 15, s4i = e & 3;
    *(floatx4*)(orow + (size_t)r * 1024 + gblk * 64 + s4i * 4) = zf4;
  }
#pragma unroll
  for (int half = 0; half < 2; ++half) {
    floatx4 vacc[3][2];
#pragma unroll
    for (int t = 0; t < 3; ++t)
#pragma unroll
      for (int j = 0; j < 2; ++j) vacc[t][j] = zf4;
    for (int kt = 0; kt < 4; ++kt) {
      short8 bf[2];
#pragma unroll
      for (int j = 0; j < 2; ++j)
        bf[j] = *(const short8*)(C_sw +
                                 (((ntg[2 * half + j] * 4 + kt) * 64 + lane) << 3));
#pragma unroll
      for (int t = 0; t < 3; ++t) {
        short8 af = *(const short8*)(v1 + t * XV_T + l15 * XV_S + kt * 32 + quad * 8);
#pragma unroll
        for (int j = 0; j < 2; ++j)
          vacc[t][j] = __builtin_amdgcn_mfma_f32_16x16x32_bf16(af, bf[j], vacc[t][j], 0, 0, 0);
      }
    }
    // Row layout: 16 groups of 64 = [16 zeros | 48 data],
    // data col = g*64 + 16 + 3*(n&15) + t with g = nt.
#pragma unroll
    for (int j = 0; j < 2; ++j) {
      int nt = ntg[2 * half + j];
#pragma unroll
      for (int rg = 0; rg < 4; ++rg) {
        int r = quad * 4 + rg;
        *(float3*)(orow + (size_t)r * 1024 + nt * 64 + 16 + 3 * l15) =
            make_float3(vacc[0][j][rg], vacc[1][j][rg], vacc[2][j][rg]);
      }
    }
  }
}

__global__ __launch_bounds__(256, 4) void main_k(
    const float* __restrict__ x, const float* __restrict__ bm0,
    const unsigned short* __restrict__ Wcat_sw,
    const unsigned short* __restrict__ Wm0_sw,
    const unsigned short* __restrict__ C_sw, float* __restrict__ out) {
  // LDS (34560 B, non-aliased): v1 [0,13056) | xa [13056,21504) | xv [21504,34560)
  // v1 separate so phase3(g0) reads overlap g1's xa/xv staging.
  __shared__ __align__(16) unsigned char smem[34560];
  unsigned short* v1 = (unsigned short*)smem;
  unsigned short* xa = (unsigned short*)(smem + 13056);
  unsigned short* xv = (unsigned short*)(smem + 21504);

  const int tid = threadIdx.x;
  const int lane = tid & 63;
  const int w = tid >> 6;
  const int l15 = lane & 15;
  const int quad = lane >> 4;
  const int g0 = blockIdx.x;          // groups g0 and g0+1024 (16 rows each)
  const int g1 = blockIdx.x + 1024;
  const float* xrow0 = x + (size_t)g0 * 16 * 512;
  const float* xrow1 = x + (size_t)g1 * 16 * 512;
  float* orow0 = out + (size_t)g0 * 16 * 1024;
  float* orow1 = out + (size_t)g1 * 16 * 1024;

  float bias0 = bm0[(2 * w) * 16 + l15];
  float bias1 = bm0[(2 * w + 1) * 16 + l15];

  float4 st_s[2], st_v[6];

  // ---- group 0 staging
  load_x(xrow0, tid, st_s, st_v);
  stage_write(tid, st_s, st_v, xa, xv);
  lds_barrier();  // B1(g0)

  // ---- issue g1 loads NOW: latency + read traffic hide under g0 compute
  load_x(xrow1, tid, st_s, st_v);

  compute_front(Wcat_sw, Wm0_sw, xa, xv, v1, lane, w, l15, quad, bias0, bias1);
  lds_barrier();  // B3(g0): xa/xv reads all complete -> g1 may claim them

  // ---- g1 staging into LDS (v1(g0) untouched; phase3(g0) still to come)
  stage_write(tid, st_s, st_v, xa, xv);

  compute_back(C_sw, v1, orow0, tid, lane, w, l15, quad);
  lds_barrier();  // B1(g1): lgkm-only -> g0 stores keep draining across it

  compute_front(Wcat_sw, Wm0_sw, xa, xv, v1, lane, w, l15, quad, bias0, bias1);
  lds_barrier();  // B3(g1)
  compute_back(C_sw, v1, orow1, tid, lane, w, l15, quad);
}

extern "C" void kernel_launch(void* const* d_in, const int* in_sizes, int n_in,
                              void* d_out, int out_size, void* d_ws,
                              size_t ws_size, hipStream_t stream) {
  const float* mo = (const float*)d_in[0];
  const float* Wh0 = (const float*)d_in[1];
  const float* Wu0 = (const float*)d_in[2];
  const float* Wm0 = (const float*)d_in[3];
  const float* bm0 = (const float*)d_in[4];
  const float* Wh1 = (const float*)d_in[5];
  const float* Wu1 = (const float*)d_in[6];
  const float* W1 = (const float*)d_in[10];
  // d_in[7]=Wm1, d_in[8]=bm1, d_in[9]=W0: dead under antisymmetrization

  unsigned short* ws = (unsigned short*)d_ws;
  unsigned short* Wcat_sw = ws;         // 64 KB
  unsigned short* C_sw = ws + 32768;    // 64 KB
  unsigned short* Wm0_sw = ws + 65536;  // 64 KB
  float* T = (float*)(ws + 98304);      // 64 KB

  prep1<<<256, 128, 0, stream>>>(Wh0, Wu0, Wh1, Wu1, Wcat_sw, T);
  prep2<<<256, 256, 0, stream>>>(T, W1, Wm0, C_sw, Wm0_sw);

  main_k<<<1024, 256, 0, stream>>>(mo, bm0, Wcat_sw, Wm0_sw, C_sw,
                                   (float*)d_out);
}

// Round 6
// 236.690 us; speedup vs baseline: 1.1071x; 1.1071x over previous
//
#include <hip/hip_runtime.h>
#include <hip/hip_bf16.h>

// E3TAOBackflow on MI355X — MFMA bf16, register-resident norms/gating.
// Reduction (verified R2/R3): antisymmetrization => scalar out = 0 exactly,
// vector out = (v @ [Wh0@Wu0]) * sigmoid([s,||v@Wh0||] @ Wm0 + bm0) @ C,
// C = Wh1@Wu1@W1/sqrt(S).  Wm1, bm1, W0 dead.  Output f32.
// t-split M: 3 GEMMs 16x128x256 sharing B-frags; cross-t norm and sigmoid
// gating stay in registers; phase3 D stores directly to global as 3 floats
// (out col = nt*64 + 16 + 3*l15 + t). 3 barriers total.
// R9 = R7 + single change: __launch_bounds__(256,6).
//   R8 post-mortem: compiler chose 64 VGPR and spilled held staging
//   (~70MB scratch write-back, main_k 91us) -> spills are catastrophic;
//   occupancy must come WITHOUT register pressure. Split-phase structure
//   (live set ~50-60 VGPR) + aliased LDS (21504B) fits the (256,6) cap
//   of 80 VGPR spill-free -> 6 blocks/CU (vs R0's 4, R7's 5). More
//   resident blocks = more overlapping load/store streams to fill HBM.
// Kept from earlier rounds: no nontemporal stores (R4: partial-line write
// amplification); zeros post-B3 where no downstream barrier forces a
// vmcnt(0) drain (R6/R7: +4us); plain __syncthreads (R0-proven; at these
// barriers no global ops are in flight, so the vmcnt drain is free).

typedef __attribute__((ext_vector_type(8))) short short8;
typedef __attribute__((ext_vector_type(4))) float floatx4;

static __device__ __forceinline__ unsigned short f2bf(float f) {
  unsigned u = __float_as_uint(f);
  u = (u + 0x7fffu + ((u >> 16) & 1u)) >> 16;  // RNE
  return (unsigned short)u;
}
static __device__ __forceinline__ unsigned pk2(float lo, float hi) {
  __hip_bfloat162 h = __float22bfloat162_rn(make_float2(lo, hi));
  return *(unsigned*)&h;  // low 16 = lo
}

// write element B[k][n] into swizzled fragment layout (KT = K/32)
static __device__ __forceinline__ void put_sw(unsigned short* B, int k, int n,
                                              float val, int KT) {
  int kt = k >> 5, quad = (k >> 3) & 3, j = k & 7;
  int nt = n >> 4, c = n & 15;
  int lane = quad * 16 + c;
  B[(((nt * KT + kt) * 64 + lane) << 3) + j] = f2bf(val);
}

// ---- prep1: Wcat = [Wh0 | Wh0@Wu0] -> Wcat_sw (128x256, KT=4); T = Wh1@Wu1
__global__ __launch_bounds__(128) void prep1(
    const float* __restrict__ Wh0, const float* __restrict__ Wu0,
    const float* __restrict__ Wh1, const float* __restrict__ Wu1,
    unsigned short* __restrict__ Wcat_sw, float* __restrict__ T) {
  int b = blockIdx.x, o = threadIdx.x;
  if (b < 128) {
    int m = b;
    float acc = 0.f;
    for (int h = 0; h < 128; ++h) acc += Wh0[m * 128 + h] * Wu0[h * 128 + o];
    put_sw(Wcat_sw, m, o, Wh0[m * 128 + o], 4);
    put_sw(Wcat_sw, m, o + 128, acc, 4);
  } else {
    int m = b - 128;
    float acc = 0.f;
    for (int h = 0; h < 128; ++h) acc += Wh1[m * 128 + h] * Wu1[h * 128 + o];
    T[m * 128 + o] = acc;
  }
}

// ---- prep2: C_sw = (T@W1)/sqrt(S) (128x256, KT=4); Wm0_sw (256x128, KT=8)
__global__ __launch_bounds__(256) void prep2(
    const float* __restrict__ T, const float* __restrict__ W1,
    const float* __restrict__ Wm0, unsigned short* __restrict__ C_sw,
    unsigned short* __restrict__ Wm0_sw) {
  int b = blockIdx.x, tid = threadIdx.x;
  if (b < 128) {
    int m = b, n = tid;
    float acc = 0.f;
    for (int h = 0; h < 128; ++h) acc += T[m * 128 + h] * W1[h * 256 + n];
    put_sw(C_sw, m, n, acc * 0.08838834764831845f, 4);
  } else {
    int k = (b - 128) * 2 + (tid >> 7);
    int n = tid & 127;
    put_sw(Wm0_sw, k, n, Wm0[k * 128 + n], 8);
  }
}

#define XA_S 264  // bf16 row stride for xa (256 + 8 pad; 528B = 33*16 ok)
#define XV_S 136  // bf16 row stride for xv/v1 (128 + 8 pad; 272B = 17*16 ok)
#define XV_T 2176 // elements per t-plane (16 * 136)

__global__ __launch_bounds__(256, 6) void main_k(
    const float* __restrict__ x, const float* __restrict__ bm0,
    const unsigned short* __restrict__ Wcat_sw,
    const unsigned short* __restrict__ Wm0_sw,
    const unsigned short* __restrict__ C_sw, float* __restrict__ out) {
  // LDS (21504 B): xv/v1 [0,13056) | xa [13056,21504)
  // v1 aliases xv: all xv reads are pre-B2, all v1 writes post-B2.
  __shared__ __align__(16) unsigned char smem[21504];
  unsigned short* xv = (unsigned short*)smem;
  unsigned short* v1 = (unsigned short*)smem;
  unsigned short* xa = (unsigned short*)(smem + 13056);

  const int tid = threadIdx.x;
  const int lane = tid & 63;
  const int w = tid >> 6;
  const int l15 = lane & 15;
  const int quad = lane >> 4;
  const int r0 = blockIdx.x << 4;  // 16 rows/block
  const float* xrow = x + (size_t)r0 * 512;
  float* orow = out + (size_t)r0 * 1024;
  const int ntg[4] = {2 * w, 2 * w + 1, 8 + 2 * w, 9 + 2 * w};

  // bias for gate cols this lane will own (needed post-gate; load early)
  float bias0 = bm0[(2 * w) * 16 + l15];
  float bias1 = bm0[(2 * w + 1) * 16 + l15];

  // ---- stage: s -> xa bf16; v -> xv[t][r][m] bf16 (packed b64 writes)
#pragma unroll
  for (int i = 0; i < 2; ++i) {  // s: 512 float4 chunks
    int e = tid + 256 * i;
    int r = e >> 5, c0 = (e & 31) << 2;
    float4 s4 = *(const float4*)(xrow + r * 512 + c0);
    uint2 p = make_uint2(pk2(s4.x, s4.y), pk2(s4.z, s4.w));
    *(uint2*)(xa + r * XA_S + c0) = p;
  }
#pragma unroll
  for (int i = 0; i < 2; ++i) {  // v: 512 chunks of 12 floats (4 m x 3 t)
    int e = tid + 256 * i;
    int r = e >> 5, mc = e & 31;
    const float* p = xrow + r * 512 + 128 + mc * 12;
    float4 a = *(const float4*)(p);
    float4 b = *(const float4*)(p + 4);
    float4 c = *(const float4*)(p + 8);
    float f[12] = {a.x, a.y, a.z, a.w, b.x, b.y, b.z, b.w, c.x, c.y, c.z, c.w};
#pragma unroll
    for (int t = 0; t < 3; ++t) {
      uint2 pk = make_uint2(pk2(f[t], f[t + 3]), pk2(f[t + 6], f[t + 9]));
      *(uint2*)(xv + t * XV_T + r * XV_S + mc * 4) = pk;
    }
  }
  __syncthreads();  // B1

  const floatx4 zf4 = {0.f, 0.f, 0.f, 0.f};

  // ---- phase1a: per t, Vh(16x32) = xv_t(16x128) @ Wcat[:, ntg01]
  floatx4 accH[3][2];
#pragma unroll
  for (int t = 0; t < 3; ++t)
#pragma unroll
    for (int j = 0; j < 2; ++j) accH[t][j] = zf4;
  for (int kt = 0; kt < 4; ++kt) {
    short8 bf[2];
#pragma unroll
    for (int j = 0; j < 2; ++j)
      bf[j] = *(const short8*)(Wcat_sw + (((ntg[j] * 4 + kt) * 64 + lane) << 3));
#pragma unroll
    for (int t = 0; t < 3; ++t) {
      short8 af = *(const short8*)(xv + t * XV_T + l15 * XV_S + kt * 32 + quad * 8);
#pragma unroll
      for (int j = 0; j < 2; ++j)
        accH[t][j] = __builtin_amdgcn_mfma_f32_16x16x32_bf16(af, bf[j], accH[t][j], 0, 0, 0);
    }
  }

  // ---- norms in registers: vn = sqrt(sum_t Vh_t^2 + eps) -> xa[:,128:]
#pragma unroll
  for (int j = 0; j < 2; ++j)
#pragma unroll
    for (int rg = 0; rg < 4; ++rg) {
      float s0 = accH[0][j][rg], s1 = accH[1][j][rg], s2 = accH[2][j][rg];
      float vn = sqrtf(s0 * s0 + s1 * s1 + s2 * s2 + 1e-8f);
      int r = quad * 4 + rg;
      int h = ntg[j] * 16 + l15;
      xa[r * XA_S + 128 + h] = f2bf(vn);
    }

  // ---- phase1b: per t, Vu(16x32) = xv_t(16x128) @ Wcat[:, ntg23]
  // (accH dead now -> register pressure stays ~32 acc VGPRs)
  floatx4 accU[3][2];
#pragma unroll
  for (int t = 0; t < 3; ++t)
#pragma unroll
    for (int j = 0; j < 2; ++j) accU[t][j] = zf4;
  for (int kt = 0; kt < 4; ++kt) {
    short8 bf[2];
#pragma unroll
    for (int j = 0; j < 2; ++j)
      bf[j] = *(const short8*)(Wcat_sw + (((ntg[2 + j] * 4 + kt) * 64 + lane) << 3));
#pragma unroll
    for (int t = 0; t < 3; ++t) {
      short8 af = *(const short8*)(xv + t * XV_T + l15 * XV_S + kt * 32 + quad * 8);
#pragma unroll
      for (int j = 0; j < 2; ++j)
        accU[t][j] = __builtin_amdgcn_mfma_f32_16x16x32_bf16(af, bf[j], accU[t][j], 0, 0, 0);
    }
  }
  __syncthreads();  // B2

  // ---- gate GEMM: sm(16x128) = [s|vn](16x256) @ Wm0; wave w -> cols 2w,2w+1
  floatx4 ga[2] = {zf4, zf4};
  for (int kt = 0; kt < 8; ++kt) {
    short8 af = *(const short8*)(xa + l15 * XA_S + kt * 32 + quad * 8);
    short8 b0 = *(const short8*)(Wm0_sw + ((((2 * w) * 8 + kt) * 64 + lane) << 3));
    short8 b1 = *(const short8*)(Wm0_sw + ((((2 * w + 1) * 8 + kt) * 64 + lane) << 3));
    ga[0] = __builtin_amdgcn_mfma_f32_16x16x32_bf16(af, b0, ga[0], 0, 0, 0);
    ga[1] = __builtin_amdgcn_mfma_f32_16x16x32_bf16(af, b1, ga[1], 0, 0, 0);
  }
  // sigmoid + gating in registers: gate D-layout == Vu acc layout (lane-exact)
  float g[2][4];
#pragma unroll
  for (int j = 0; j < 2; ++j) {
    float bias = j ? bias1 : bias0;
#pragma unroll
    for (int rg = 0; rg < 4; ++rg)
      g[j][rg] = 1.f / (1.f + __expf(-(ga[j][rg] + bias)));
  }
#pragma unroll
  for (int t = 0; t < 3; ++t)
#pragma unroll
    for (int j = 0; j < 2; ++j)
#pragma unroll
      for (int rg = 0; rg < 4; ++rg) {
        int r = quad * 4 + rg;
        int o = (2 * w + j) * 16 + l15;  // Vu col within [0,128)
        v1[t * XV_T + r * XV_S + o] = f2bf(accU[t][j][rg] * g[j][rg]);
      }
  __syncthreads();  // B3

  // ---- zero-stores for out: post-B3 — no downstream barrier, so no forced
  // vmcnt(0) drain; they trickle out under phase3 MFMA.
#pragma unroll
  for (int i = 0; i < 4; ++i) {  // zeros: 1024 float4
    int e = tid + 256 * i;
    int r = e >> 6, gblk = (e >> 2) & 15, s4i = e & 3;
    *(floatx4*)(orow + (size_t)r * 1024 + gblk * 64 + s4i * 4) = zf4;
  }

  // ---- phase3: per t, vo_t(16x256) = v1_t(16x128) @ C; two halves, each
  // half's stores issue before the next half's MFMA (spreads store burst,
  // halves vacc live set).
#pragma unroll
  for (int half = 0; half < 2; ++half) {
    floatx4 vacc[3][2];
#pragma unroll
    for (int t = 0; t < 3; ++t)
#pragma unroll
      for (int j = 0; j < 2; ++j) vacc[t][j] = zf4;
    for (int kt = 0; kt < 4; ++kt) {
      short8 bf[2];
#pragma unroll
      for (int j = 0; j < 2; ++j)
        bf[j] = *(const short8*)(C_sw +
                                 (((ntg[2 * half + j] * 4 + kt) * 64 + lane) << 3));
#pragma unroll
      for (int t = 0; t < 3; ++t) {
        short8 af = *(const short8*)(v1 + t * XV_T + l15 * XV_S + kt * 32 + quad * 8);
#pragma unroll
        for (int j = 0; j < 2; ++j)
          vacc[t][j] = __builtin_amdgcn_mfma_f32_16x16x32_bf16(af, bf[j], vacc[t][j], 0, 0, 0);
      }
    }
    // stores for this half. Row layout: 16 groups of 64 = [16 zeros | 48
    // data], data col = g*64 + 16 + 3*(n&15) + t with g = nt.
#pragma unroll
    for (int j = 0; j < 2; ++j) {
      int nt = ntg[2 * half + j];
#pragma unroll
      for (int rg = 0; rg < 4; ++rg) {
        int r = quad * 4 + rg;
        *(float3*)(orow + (size_t)r * 1024 + nt * 64 + 16 + 3 * l15) =
            make_float3(vacc[0][j][rg], vacc[1][j][rg], vacc[2][j][rg]);
      }
    }
  }
}

extern "C" void kernel_launch(void* const* d_in, const int* in_sizes, int n_in,
                              void* d_out, int out_size, void* d_ws,
                              size_t ws_size, hipStream_t stream) {
  const float* mo = (const float*)d_in[0];
  const float* Wh0 = (const float*)d_in[1];
  const float* Wu0 = (const float*)d_in[2];
  const float* Wm0 = (const float*)d_in[3];
  const float* bm0 = (const float*)d_in[4];
  const float* Wh1 = (const float*)d_in[5];
  const float* Wu1 = (const float*)d_in[6];
  const float* W1 = (const float*)d_in[10];
  // d_in[7]=Wm1, d_in[8]=bm1, d_in[9]=W0: dead under antisymmetrization

  unsigned short* ws = (unsigned short*)d_ws;
  unsigned short* Wcat_sw = ws;         // 64 KB
  unsigned short* C_sw = ws + 32768;    // 64 KB
  unsigned short* Wm0_sw = ws + 65536;  // 64 KB
  float* T = (float*)(ws + 98304);      // 64 KB

  prep1<<<256, 128, 0, stream>>>(Wh0, Wu0, Wh1, Wu1, Wcat_sw, T);
  prep2<<<256, 256, 0, stream>>>(T, W1, Wm0, C_sw, Wm0_sw);

  main_k<<<2048, 256, 0, stream>>>(mo, bm0, Wcat_sw, Wm0_sw, C_sw,
                                   (float*)d_out);
}

// Round 7
// 235.555 us; speedup vs baseline: 1.1125x; 1.0048x over previous
//
#include <hip/hip_runtime.h>
#include <hip/hip_bf16.h>

// E3TAOBackflow on MI355X — MFMA bf16, register-resident norms/gating.
// Reduction (verified R2/R3): antisymmetrization => scalar out = 0 exactly,
// vector out = (v @ [Wh0@Wu0]) * sigmoid([s,||v@Wh0||] @ Wm0 + bm0) @ C,
// C = Wh1@Wu1@W1/sqrt(S).  Wm1, bm1, W0 dead.  Output f32.
// t-split M: 3 GEMMs 16x128x256 sharing B-frags; cross-t norm and sigmoid
// gating stay in registers (D-layouts align); phase3 D stores directly to
// global as float3 (out col = nt*64 + 16 + 3*l15 + t). 3 barriers total.
// R10: EXACT R0 structure ((256,4), monolithic phase1, unaliased 34560B
// LDS — occupancy ladder R7/R9 proved (256,5)/(256,6) regress ~5us each).
// Single change vs R0: the 32MB of output zeros move out of the compute
// blocks' tail burst into 512 LEADING zero-fill blocks (grid 2560,
// bid<512). They dispatch first and stream zeros at ~fill BW while gen-1
// compute blocks are in load/compute (write pipe idle); compute blocks'
// store tail shrinks 25% (64->48KB), cutting the convoy drain.
// Zero lines (cols 0..15 of each 64-col group) are whole 64B lines
// disjoint from data lines -> no ordering hazard.

typedef __attribute__((ext_vector_type(8))) short short8;
typedef __attribute__((ext_vector_type(4))) float floatx4;

static __device__ __forceinline__ unsigned short f2bf(float f) {
  unsigned u = __float_as_uint(f);
  u = (u + 0x7fffu + ((u >> 16) & 1u)) >> 16;  // RNE
  return (unsigned short)u;
}
static __device__ __forceinline__ unsigned pk2(float lo, float hi) {
  __hip_bfloat162 h = __float22bfloat162_rn(make_float2(lo, hi));
  return *(unsigned*)&h;  // low 16 = lo
}

// write element B[k][n] into swizzled fragment layout (KT = K/32)
static __device__ __forceinline__ void put_sw(unsigned short* B, int k, int n,
                                              float val, int KT) {
  int kt = k >> 5, quad = (k >> 3) & 3, j = k & 7;
  int nt = n >> 4, c = n & 15;
  int lane = quad * 16 + c;
  B[(((nt * KT + kt) * 64 + lane) << 3) + j] = f2bf(val);
}

// ---- prep1: Wcat = [Wh0 | Wh0@Wu0] -> Wcat_sw (128x256, KT=4); T = Wh1@Wu1
__global__ __launch_bounds__(128) void prep1(
    const float* __restrict__ Wh0, const float* __restrict__ Wu0,
    const float* __restrict__ Wh1, const float* __restrict__ Wu1,
    unsigned short* __restrict__ Wcat_sw, float* __restrict__ T) {
  int b = blockIdx.x, o = threadIdx.x;
  if (b < 128) {
    int m = b;
    float acc = 0.f;
    for (int h = 0; h < 128; ++h) acc += Wh0[m * 128 + h] * Wu0[h * 128 + o];
    put_sw(Wcat_sw, m, o, Wh0[m * 128 + o], 4);
    put_sw(Wcat_sw, m, o + 128, acc, 4);
  } else {
    int m = b - 128;
    float acc = 0.f;
    for (int h = 0; h < 128; ++h) acc += Wh1[m * 128 + h] * Wu1[h * 128 + o];
    T[m * 128 + o] = acc;
  }
}

// ---- prep2: C_sw = (T@W1)/sqrt(S) (128x256, KT=4); Wm0_sw (256x128, KT=8)
__global__ __launch_bounds__(256) void prep2(
    const float* __restrict__ T, const float* __restrict__ W1,
    const float* __restrict__ Wm0, unsigned short* __restrict__ C_sw,
    unsigned short* __restrict__ Wm0_sw) {
  int b = blockIdx.x, tid = threadIdx.x;
  if (b < 128) {
    int m = b, n = tid;
    float acc = 0.f;
    for (int h = 0; h < 128; ++h) acc += T[m * 128 + h] * W1[h * 256 + n];
    put_sw(C_sw, m, n, acc * 0.08838834764831845f, 4);
  } else {
    int k = (b - 128) * 2 + (tid >> 7);
    int n = tid & 127;
    put_sw(Wm0_sw, k, n, Wm0[k * 128 + n], 8);
  }
}

#define XA_S 264  // bf16 row stride for xa (256 + 8 pad; 528B = 33*16 ok)
#define XV_S 136  // bf16 row stride for xv/v1 (128 + 8 pad; 272B = 17*16 ok)
#define XV_T 2176 // elements per t-plane (16 * 136)
#define ZBLK 512  // leading zero-fill blocks

__global__ __launch_bounds__(256, 4) void main_k(
    const float* __restrict__ x, const float* __restrict__ bm0,
    const unsigned short* __restrict__ Wcat_sw,
    const unsigned short* __restrict__ Wm0_sw,
    const unsigned short* __restrict__ C_sw, float* __restrict__ out) {
  const int tid = threadIdx.x;
  const floatx4 zf4 = {0.f, 0.f, 0.f, 0.f};

  // ---- zero-fill blocks: dispatch first, stream the 32MB of zero lines
  // (cols 0..15 of each 64-float group) while compute blocks load/compute.
  if (blockIdx.x < ZBLK) {
    // 32768 rows x 64 float4 of zeros = 2M float4; 512 blocks x 256 thr
    // x 16 iters. e -> row = e>>6, idx = e&63 -> col = (idx>>2)*64+(idx&3)*4.
#pragma unroll
    for (int i = 0; i < 16; ++i) {
      unsigned e = (blockIdx.x * 256 + tid) + (unsigned)i * (ZBLK * 256);
      unsigned row = e >> 6, idx = e & 63;
      *(floatx4*)(out + (size_t)row * 1024 + (idx >> 2) * 64 + (idx & 3) * 4) =
          zf4;
    }
    return;
  }

  // LDS (34560 B): v1 [0,13056) | xa [13056,21504) | xv [21504,34560)
  __shared__ __align__(16) unsigned char smem[34560];
  unsigned short* v1 = (unsigned short*)smem;
  unsigned short* xa = (unsigned short*)(smem + 13056);
  unsigned short* xv = (unsigned short*)(smem + 21504);

  const int lane = tid & 63;
  const int w = tid >> 6;
  const int l15 = lane & 15;
  const int quad = lane >> 4;
  const int r0 = (blockIdx.x - ZBLK) << 4;  // 16 rows/block
  const float* xrow = x + (size_t)r0 * 512;
  const int ntg[4] = {2 * w, 2 * w + 1, 8 + 2 * w, 9 + 2 * w};

  // bias for gate cols this lane will own (needed post-gate; load early)
  float bias0 = bm0[(2 * w) * 16 + l15];
  float bias1 = bm0[(2 * w + 1) * 16 + l15];

  // ---- stage: s -> xa bf16; v -> xv[t][r][m] bf16 (packed b64 writes)
#pragma unroll
  for (int i = 0; i < 2; ++i) {  // s: 512 float4 chunks
    int e = tid + 256 * i;
    int r = e >> 5, c0 = (e & 31) << 2;
    float4 s4 = *(const float4*)(xrow + r * 512 + c0);
    uint2 p = make_uint2(pk2(s4.x, s4.y), pk2(s4.z, s4.w));
    *(uint2*)(xa + r * XA_S + c0) = p;
  }
#pragma unroll
  for (int i = 0; i < 2; ++i) {  // v: 512 chunks of 12 floats (4 m x 3 t)
    int e = tid + 256 * i;
    int r = e >> 5, mc = e & 31;
    const float* p = xrow + r * 512 + 128 + mc * 12;
    float4 a = *(const float4*)(p);
    float4 b = *(const float4*)(p + 4);
    float4 c = *(const float4*)(p + 8);
    float f[12] = {a.x, a.y, a.z, a.w, b.x, b.y, b.z, b.w, c.x, c.y, c.z, c.w};
#pragma unroll
    for (int t = 0; t < 3; ++t) {
      uint2 pk = make_uint2(pk2(f[t], f[t + 3]), pk2(f[t + 6], f[t + 9]));
      *(uint2*)(xv + t * XV_T + r * XV_S + mc * 4) = pk;
    }
  }
  __syncthreads();  // B1

  // ---- phase1: per t, [Vh|Vu](16x256) = xv_t(16x128) @ Wcat; B shared over t
  floatx4 acc[3][4];
#pragma unroll
  for (int t = 0; t < 3; ++t)
#pragma unroll
    for (int j = 0; j < 4; ++j) acc[t][j] = zf4;
  for (int kt = 0; kt < 4; ++kt) {
    short8 bf[4];
#pragma unroll
    for (int j = 0; j < 4; ++j)
      bf[j] = *(const short8*)(Wcat_sw + (((ntg[j] * 4 + kt) * 64 + lane) << 3));
#pragma unroll
    for (int t = 0; t < 3; ++t) {
      short8 af = *(const short8*)(xv + t * XV_T + l15 * XV_S + kt * 32 + quad * 8);
#pragma unroll
      for (int j = 0; j < 4; ++j)
        acc[t][j] = __builtin_amdgcn_mfma_f32_16x16x32_bf16(af, bf[j], acc[t][j], 0, 0, 0);
    }
  }

  // ---- norms in registers: vn = sqrt(sum_t Vh_t^2 + eps) -> xa[:,128:]
#pragma unroll
  for (int j = 0; j < 2; ++j)
#pragma unroll
    for (int rg = 0; rg < 4; ++rg) {
      float s0 = acc[0][j][rg], s1 = acc[1][j][rg], s2 = acc[2][j][rg];
      float vn = sqrtf(s0 * s0 + s1 * s1 + s2 * s2 + 1e-8f);
      int r = quad * 4 + rg;
      int h = ntg[j] * 16 + l15;
      xa[r * XA_S + 128 + h] = f2bf(vn);
    }
  __syncthreads();  // B2

  // ---- gate GEMM: sm(16x128) = [s|vn](16x256) @ Wm0; wave w -> cols 2w,2w+1
  floatx4 ga[2] = {zf4, zf4};
  for (int kt = 0; kt < 8; ++kt) {
    short8 af = *(const short8*)(xa + l15 * XA_S + kt * 32 + quad * 8);
    short8 b0 = *(const short8*)(Wm0_sw + ((((2 * w) * 8 + kt) * 64 + lane) << 3));
    short8 b1 = *(const short8*)(Wm0_sw + ((((2 * w + 1) * 8 + kt) * 64 + lane) << 3));
    ga[0] = __builtin_amdgcn_mfma_f32_16x16x32_bf16(af, b0, ga[0], 0, 0, 0);
    ga[1] = __builtin_amdgcn_mfma_f32_16x16x32_bf16(af, b1, ga[1], 0, 0, 0);
  }
  // sigmoid + gating in registers: gate D-layout == Vu acc layout (lane-exact)
  float g[2][4];
#pragma unroll
  for (int j = 0; j < 2; ++j) {
    float bias = j ? bias1 : bias0;
#pragma unroll
    for (int rg = 0; rg < 4; ++rg)
      g[j][rg] = 1.f / (1.f + __expf(-(ga[j][rg] + bias)));
  }
#pragma unroll
  for (int t = 0; t < 3; ++t)
#pragma unroll
    for (int j = 0; j < 2; ++j)
#pragma unroll
      for (int rg = 0; rg < 4; ++rg) {
        int r = quad * 4 + rg;
        int o = (2 * w + j) * 16 + l15;  // Vu col within [0,128)
        v1[t * XV_T + r * XV_S + o] = f2bf(acc[t][2 + j][rg] * g[j][rg]);
      }
  __syncthreads();  // B3

  // ---- phase3: per t, vo_t(16x256) = v1_t(16x128) @ C; B shared over t
  floatx4 vacc[3][4];
#pragma unroll
  for (int t = 0; t < 3; ++t)
#pragma unroll
    for (int j = 0; j < 4; ++j) vacc[t][j] = zf4;
  for (int kt = 0; kt < 4; ++kt) {
    short8 bf[4];
#pragma unroll
    for (int j = 0; j < 4; ++j)
      bf[j] = *(const short8*)(C_sw + (((ntg[j] * 4 + kt) * 64 + lane) << 3));
#pragma unroll
    for (int t = 0; t < 3; ++t) {
      short8 af = *(const short8*)(v1 + t * XV_T + l15 * XV_S + kt * 32 + quad * 8);
#pragma unroll
      for (int j = 0; j < 4; ++j)
        vacc[t][j] = __builtin_amdgcn_mfma_f32_16x16x32_bf16(af, bf[j], vacc[t][j], 0, 0, 0);
    }
  }

  // ---- epilogue: data stores only (zeros handled by zero-fill blocks).
  // Row layout: 16 groups of 64 = [16 zeros | 48 data],
  // data col = g*64 + 16 + 3*(n&15) + t with g = n>>4 = nt.
  float* orow = out + (size_t)r0 * 1024;
#pragma unroll
  for (int j = 0; j < 4; ++j) {
    int nt = ntg[j];
#pragma unroll
    for (int rg = 0; rg < 4; ++rg) {
      int r = quad * 4 + rg;
      *(float3*)(orow + (size_t)r * 1024 + nt * 64 + 16 + 3 * l15) =
          make_float3(vacc[0][j][rg], vacc[1][j][rg], vacc[2][j][rg]);
    }
  }
}

extern "C" void kernel_launch(void* const* d_in, const int* in_sizes, int n_in,
                              void* d_out, int out_size, void* d_ws,
                              size_t ws_size, hipStream_t stream) {
  const float* mo = (const float*)d_in[0];
  const float* Wh0 = (const float*)d_in[1];
  const float* Wu0 = (const float*)d_in[2];
  const float* Wm0 = (const float*)d_in[3];
  const float* bm0 = (const float*)d_in[4];
  const float* Wh1 = (const float*)d_in[5];
  const float* Wu1 = (const float*)d_in[6];
  const float* W1 = (const float*)d_in[10];
  // d_in[7]=Wm1, d_in[8]=bm1, d_in[9]=W0: dead under antisymmetrization

  unsigned short* ws = (unsigned short*)d_ws;
  unsigned short* Wcat_sw = ws;         // 64 KB
  unsigned short* C_sw = ws + 32768;    // 64 KB
  unsigned short* Wm0_sw = ws + 65536;  // 64 KB
  float* T = (float*)(ws + 98304);      // 64 KB

  prep1<<<256, 128, 0, stream>>>(Wh0, Wu0, Wh1, Wu1, Wcat_sw, T);
  prep2<<<256, 256, 0, stream>>>(T, W1, Wm0, C_sw, Wm0_sw);

  main_k<<<2048 + ZBLK, 256, 0, stream>>>(mo, bm0, Wcat_sw, Wm0_sw, C_sw,
                                          (float*)d_out);
}

// Round 8
// 225.506 us; speedup vs baseline: 1.1621x; 1.0446x over previous
//
#include <hip/hip_runtime.h>
#include <hip/hip_bf16.h>

// E3TAOBackflow on MI355X — MFMA bf16, register-resident norms/gating.
// Reduction (verified R2/R3): antisymmetrization => scalar out = 0 exactly,
// vector out = (v @ [Wh0@Wu0]) * sigmoid([s,||v@Wh0||] @ Wm0 + bm0) @ C,
// C = Wh1@Wu1@W1/sqrt(S).  Wm1, bm1, W0 dead.  Output f32.
// t-split M: 3 GEMMs 16x128x256 sharing B-frags; cross-t norm and sigmoid
// gating stay in registers (D-layouts align); phase3 D stores directly to
// global as float3 (out col = nt*64 + 16 + 3*l15 + t). 3 barriers total.
// R11: byte-exact revert to R0 (225.6us). The full ladder of deviations —
// occupancy (256,{5,6}), store placement (post-B1/post-B3/leading zero
// blocks), nontemporal, 2-group pipelining with lgkm-only barriers —
// regressed 6-36us each (R4-R10). R0 is the measured local optimum:
// zeros+data in the tail burst, (256,4), monolithic phase1, unaliased LDS.

typedef __attribute__((ext_vector_type(8))) short short8;
typedef __attribute__((ext_vector_type(4))) float floatx4;

static __device__ __forceinline__ unsigned short f2bf(float f) {
  unsigned u = __float_as_uint(f);
  u = (u + 0x7fffu + ((u >> 16) & 1u)) >> 16;  // RNE
  return (unsigned short)u;
}
static __device__ __forceinline__ unsigned pk2(float lo, float hi) {
  __hip_bfloat162 h = __float22bfloat162_rn(make_float2(lo, hi));
  return *(unsigned*)&h;  // low 16 = lo
}

// write element B[k][n] into swizzled fragment layout (KT = K/32)
static __device__ __forceinline__ void put_sw(unsigned short* B, int k, int n,
                                              float val, int KT) {
  int kt = k >> 5, quad = (k >> 3) & 3, j = k & 7;
  int nt = n >> 4, c = n & 15;
  int lane = quad * 16 + c;
  B[(((nt * KT + kt) * 64 + lane) << 3) + j] = f2bf(val);
}

// ---- prep1: Wcat = [Wh0 | Wh0@Wu0] -> Wcat_sw (128x256, KT=4); T = Wh1@Wu1
__global__ __launch_bounds__(128) void prep1(
    const float* __restrict__ Wh0, const float* __restrict__ Wu0,
    const float* __restrict__ Wh1, const float* __restrict__ Wu1,
    unsigned short* __restrict__ Wcat_sw, float* __restrict__ T) {
  int b = blockIdx.x, o = threadIdx.x;
  if (b < 128) {
    int m = b;
    float acc = 0.f;
    for (int h = 0; h < 128; ++h) acc += Wh0[m * 128 + h] * Wu0[h * 128 + o];
    put_sw(Wcat_sw, m, o, Wh0[m * 128 + o], 4);
    put_sw(Wcat_sw, m, o + 128, acc, 4);
  } else {
    int m = b - 128;
    float acc = 0.f;
    for (int h = 0; h < 128; ++h) acc += Wh1[m * 128 + h] * Wu1[h * 128 + o];
    T[m * 128 + o] = acc;
  }
}

// ---- prep2: C_sw = (T@W1)/sqrt(S) (128x256, KT=4); Wm0_sw (256x128, KT=8)
__global__ __launch_bounds__(256) void prep2(
    const float* __restrict__ T, const float* __restrict__ W1,
    const float* __restrict__ Wm0, unsigned short* __restrict__ C_sw,
    unsigned short* __restrict__ Wm0_sw) {
  int b = blockIdx.x, tid = threadIdx.x;
  if (b < 128) {
    int m = b, n = tid;
    float acc = 0.f;
    for (int h = 0; h < 128; ++h) acc += T[m * 128 + h] * W1[h * 256 + n];
    put_sw(C_sw, m, n, acc * 0.08838834764831845f, 4);
  } else {
    int k = (b - 128) * 2 + (tid >> 7);
    int n = tid & 127;
    put_sw(Wm0_sw, k, n, Wm0[k * 128 + n], 8);
  }
}

#define XA_S 264  // bf16 row stride for xa (256 + 8 pad; 528B = 33*16 ok)
#define XV_S 136  // bf16 row stride for xv/v1 (128 + 8 pad; 272B = 17*16 ok)
#define XV_T 2176 // elements per t-plane (16 * 136)

__global__ __launch_bounds__(256, 4) void main_k(
    const float* __restrict__ x, const float* __restrict__ bm0,
    const unsigned short* __restrict__ Wcat_sw,
    const unsigned short* __restrict__ Wm0_sw,
    const unsigned short* __restrict__ C_sw, float* __restrict__ out) {
  // LDS (34560 B): v1 [0,13056) | xa [13056,21504) | xv [21504,34560)
  __shared__ __align__(16) unsigned char smem[34560];
  unsigned short* v1 = (unsigned short*)smem;
  unsigned short* xa = (unsigned short*)(smem + 13056);
  unsigned short* xv = (unsigned short*)(smem + 21504);

  const int tid = threadIdx.x;
  const int lane = tid & 63;
  const int w = tid >> 6;
  const int l15 = lane & 15;
  const int quad = lane >> 4;
  const int r0 = blockIdx.x << 4;  // 16 rows/block
  const float* xrow = x + (size_t)r0 * 512;
  const int ntg[4] = {2 * w, 2 * w + 1, 8 + 2 * w, 9 + 2 * w};

  // bias for gate cols this lane will own (needed post-gate; load early)
  float bias0 = bm0[(2 * w) * 16 + l15];
  float bias1 = bm0[(2 * w + 1) * 16 + l15];

  // ---- stage: s -> xa bf16; v -> xv[t][r][m] bf16 (packed b64 writes)
#pragma unroll
  for (int i = 0; i < 2; ++i) {  // s: 512 float4 chunks
    int e = tid + 256 * i;
    int r = e >> 5, c0 = (e & 31) << 2;
    float4 s4 = *(const float4*)(xrow + r * 512 + c0);
    uint2 p = make_uint2(pk2(s4.x, s4.y), pk2(s4.z, s4.w));
    *(uint2*)(xa + r * XA_S + c0) = p;
  }
#pragma unroll
  for (int i = 0; i < 2; ++i) {  // v: 512 chunks of 12 floats (4 m x 3 t)
    int e = tid + 256 * i;
    int r = e >> 5, mc = e & 31;
    const float* p = xrow + r * 512 + 128 + mc * 12;
    float4 a = *(const float4*)(p);
    float4 b = *(const float4*)(p + 4);
    float4 c = *(const float4*)(p + 8);
    float f[12] = {a.x, a.y, a.z, a.w, b.x, b.y, b.z, b.w, c.x, c.y, c.z, c.w};
#pragma unroll
    for (int t = 0; t < 3; ++t) {
      uint2 pk = make_uint2(pk2(f[t], f[t + 3]), pk2(f[t + 6], f[t + 9]));
      *(uint2*)(xv + t * XV_T + r * XV_S + mc * 4) = pk;
    }
  }
  __syncthreads();  // B1

  const floatx4 zf4 = {0.f, 0.f, 0.f, 0.f};

  // ---- phase1: per t, [Vh|Vu](16x256) = xv_t(16x128) @ Wcat; B shared over t
  floatx4 acc[3][4];
#pragma unroll
  for (int t = 0; t < 3; ++t)
#pragma unroll
    for (int j = 0; j < 4; ++j) acc[t][j] = zf4;
  for (int kt = 0; kt < 4; ++kt) {
    short8 bf[4];
#pragma unroll
    for (int j = 0; j < 4; ++j)
      bf[j] = *(const short8*)(Wcat_sw + (((ntg[j] * 4 + kt) * 64 + lane) << 3));
#pragma unroll
    for (int t = 0; t < 3; ++t) {
      short8 af = *(const short8*)(xv + t * XV_T + l15 * XV_S + kt * 32 + quad * 8);
#pragma unroll
      for (int j = 0; j < 4; ++j)
        acc[t][j] = __builtin_amdgcn_mfma_f32_16x16x32_bf16(af, bf[j], acc[t][j], 0, 0, 0);
    }
  }

  // ---- norms in registers: vn = sqrt(sum_t Vh_t^2 + eps) -> xa[:,128:]
#pragma unroll
  for (int j = 0; j < 2; ++j)
#pragma unroll
    for (int rg = 0; rg < 4; ++rg) {
      float s0 = acc[0][j][rg], s1 = acc[1][j][rg], s2 = acc[2][j][rg];
      float vn = sqrtf(s0 * s0 + s1 * s1 + s2 * s2 + 1e-8f);
      int r = quad * 4 + rg;
      int h = ntg[j] * 16 + l15;
      xa[r * XA_S + 128 + h] = f2bf(vn);
    }
  __syncthreads();  // B2

  // ---- gate GEMM: sm(16x128) = [s|vn](16x256) @ Wm0; wave w -> cols 2w,2w+1
  floatx4 ga[2] = {zf4, zf4};
  for (int kt = 0; kt < 8; ++kt) {
    short8 af = *(const short8*)(xa + l15 * XA_S + kt * 32 + quad * 8);
    short8 b0 = *(const short8*)(Wm0_sw + ((((2 * w) * 8 + kt) * 64 + lane) << 3));
    short8 b1 = *(const short8*)(Wm0_sw + ((((2 * w + 1) * 8 + kt) * 64 + lane) << 3));
    ga[0] = __builtin_amdgcn_mfma_f32_16x16x32_bf16(af, b0, ga[0], 0, 0, 0);
    ga[1] = __builtin_amdgcn_mfma_f32_16x16x32_bf16(af, b1, ga[1], 0, 0, 0);
  }
  // sigmoid + gating in registers: gate D-layout == Vu acc layout (lane-exact)
  float g[2][4];
#pragma unroll
  for (int j = 0; j < 2; ++j) {
    float bias = j ? bias1 : bias0;
#pragma unroll
    for (int rg = 0; rg < 4; ++rg)
      g[j][rg] = 1.f / (1.f + __expf(-(ga[j][rg] + bias)));
  }
#pragma unroll
  for (int t = 0; t < 3; ++t)
#pragma unroll
    for (int j = 0; j < 2; ++j)
#pragma unroll
      for (int rg = 0; rg < 4; ++rg) {
        int r = quad * 4 + rg;
        int o = (2 * w + j) * 16 + l15;  // Vu col within [0,128)
        v1[t * XV_T + r * XV_S + o] = f2bf(acc[t][2 + j][rg] * g[j][rg]);
      }
  __syncthreads();  // B3

  // ---- phase3: per t, vo_t(16x256) = v1_t(16x128) @ C; B shared over t
  floatx4 vacc[3][4];
#pragma unroll
  for (int t = 0; t < 3; ++t)
#pragma unroll
    for (int j = 0; j < 4; ++j) vacc[t][j] = zf4;
  for (int kt = 0; kt < 4; ++kt) {
    short8 bf[4];
#pragma unroll
    for (int j = 0; j < 4; ++j)
      bf[j] = *(const short8*)(C_sw + (((ntg[j] * 4 + kt) * 64 + lane) << 3));
#pragma unroll
    for (int t = 0; t < 3; ++t) {
      short8 af = *(const short8*)(v1 + t * XV_T + l15 * XV_S + kt * 32 + quad * 8);
#pragma unroll
      for (int j = 0; j < 4; ++j)
        vacc[t][j] = __builtin_amdgcn_mfma_f32_16x16x32_bf16(af, bf[j], vacc[t][j], 0, 0, 0);
    }
  }

  // ---- epilogue: direct stores. Row layout: 16 groups of 64 = [16 zeros |
  // 48 data], data col = g*64 + 16 + 3*(n&15) + t with g = n>>4 = nt.
  float* orow = out + (size_t)r0 * 1024;
#pragma unroll
  for (int i = 0; i < 4; ++i) {  // zeros: 1024 float4
    int e = tid + 256 * i;
    int r = e >> 6, gblk = (e >> 2) & 15, s4 = e & 3;
    *(float4*)(orow + (size_t)r * 1024 + gblk * 64 + s4 * 4) =
        make_float4(0.f, 0.f, 0.f, 0.f);
  }
#pragma unroll
  for (int j = 0; j < 4; ++j) {
    int nt = ntg[j];
#pragma unroll
    for (int rg = 0; rg < 4; ++rg) {
      int r = quad * 4 + rg;
      *(float3*)(orow + (size_t)r * 1024 + nt * 64 + 16 + 3 * l15) =
          make_float3(vacc[0][j][rg], vacc[1][j][rg], vacc[2][j][rg]);
    }
  }
}

extern "C" void kernel_launch(void* const* d_in, const int* in_sizes, int n_in,
                              void* d_out, int out_size, void* d_ws,
                              size_t ws_size, hipStream_t stream) {
  const float* mo = (const float*)d_in[0];
  const float* Wh0 = (const float*)d_in[1];
  const float* Wu0 = (const float*)d_in[2];
  const float* Wm0 = (const float*)d_in[3];
  const float* bm0 = (const float*)d_in[4];
  const float* Wh1 = (const float*)d_in[5];
  const float* Wu1 = (const float*)d_in[6];
  const float* W1 = (const float*)d_in[10];
  // d_in[7]=Wm1, d_in[8]=bm1, d_in[9]=W0: dead under antisymmetrization

  unsigned short* ws = (unsigned short*)d_ws;
  unsigned short* Wcat_sw = ws;         // 64 KB
  unsigned short* C_sw = ws + 32768;    // 64 KB
  unsigned short* Wm0_sw = ws + 65536;  // 64 KB
  float* T = (float*)(ws + 98304);      // 64 KB

  prep1<<<256, 128, 0, stream>>>(Wh0, Wu0, Wh1, Wu1, Wcat_sw, T);
  prep2<<<256, 256, 0, stream>>>(T, W1, Wm0, C_sw, Wm0_sw);

  main_k<<<2048, 256, 0, stream>>>(mo, bm0, Wcat_sw, Wm0_sw, C_sw,
                                   (float*)d_out);
}